// Round 1
// baseline (96.409 us; speedup 1.0000x reference)
//
#include <hip/hip_runtime.h>
#include <stdint.h>

// Tropical (max-plus) GEMM: out[b,o] = max_i ( W[o,i] + X[b,i] * factors[o] )
// B=512, OUT=1024, IN=1024, f32. VALU-bound (no MFMA for max-reduction).
// Strategy: 64x64 output tiles, 4x4 regs/thread, LDS-staged transposed tiles,
// split-K x4 for 512 blocks (2/CU), combine via atomicMax on monotone u32 keys.

#define BDIM 512
#define OUTDIM 1024
#define INDIM 1024
#define BM 64
#define BN 64
#define BK 32
#define SPLITK 4
#define KCHUNK (INDIM / SPLITK)   // 256

// Monotone f32 -> u32 key (order-preserving for all non-NaN floats).
__device__ __forceinline__ unsigned enc_f32(float f) {
    unsigned u = __float_as_uint(f);
    return (u & 0x80000000u) ? ~u : (u | 0x80000000u);
}
__device__ __forceinline__ float dec_f32(unsigned k) {
    unsigned u = (k & 0x80000000u) ? (k & 0x7FFFFFFFu) : ~k;
    return __uint_as_float(u);
}

__global__ __launch_bounds__(256, 2)
void smp_main_kernel(const float* __restrict__ X, const float* __restrict__ W,
                     const float* __restrict__ F, unsigned* __restrict__ outk) {
    // Transposed tiles: Ts[i][row]; row-stride BM+4 keeps 16B alignment for b128
    // reads and breaks the worst bank patterns on the transpose writes.
    __shared__ float Xs[BK][BM + 4];
    __shared__ float Ws[BK][BN + 4];
    __shared__ float Os[BM][BN + 1];   // epilogue shuffle tile (stride 65: 2-way reads)

    const int tid = threadIdx.x;
    const int tx = tid & 15;    // b-quad index   (16 x 4 = 64 rows)
    const int ty = tid >> 4;    // o-quad index   (16 x 4 = 64 cols)
    const int ob = blockIdx.x * BN;
    const int bb = blockIdx.y * BM;
    const int kbase = blockIdx.z * KCHUNK;

    float f[4];
#pragma unroll
    for (int n = 0; n < 4; ++n) f[n] = F[ob + 4 * ty + n];

    float acc[4][4];
#pragma unroll
    for (int m = 0; m < 4; ++m)
#pragma unroll
        for (int n = 0; n < 4; ++n) acc[m][n] = -INFINITY;

    for (int kt = 0; kt < KCHUNK; kt += BK) {
        // ---- stage: 64x32 X-tile and 64x32 W-tile, transposed into LDS ----
#pragma unroll
        for (int r = 0; r < 2; ++r) {
            const int l2 = tid + r * 256;
            const int row = l2 >> 3;          // 0..63
            const int c4 = (l2 & 7) * 4;      // 0..28
            const float4 xv = *reinterpret_cast<const float4*>(
                &X[(size_t)(bb + row) * INDIM + kbase + kt + c4]);
            const float4 wv = *reinterpret_cast<const float4*>(
                &W[(size_t)(ob + row) * INDIM + kbase + kt + c4]);
            Xs[c4 + 0][row] = xv.x; Xs[c4 + 1][row] = xv.y;
            Xs[c4 + 2][row] = xv.z; Xs[c4 + 3][row] = xv.w;
            Ws[c4 + 0][row] = wv.x; Ws[c4 + 1][row] = wv.y;
            Ws[c4 + 2][row] = wv.z; Ws[c4 + 3][row] = wv.w;
        }
        __syncthreads();

        // ---- compute: 2x ds_read_b128 + 16 fma + 16 max per i ----
#pragma unroll
        for (int i = 0; i < BK; ++i) {
            const float4 xv = *reinterpret_cast<const float4*>(&Xs[i][4 * tx]);
            const float4 wv = *reinterpret_cast<const float4*>(&Ws[i][4 * ty]);
            const float x[4] = {xv.x, xv.y, xv.z, xv.w};
            const float w[4] = {wv.x, wv.y, wv.z, wv.w};
#pragma unroll
            for (int m = 0; m < 4; ++m)
#pragma unroll
                for (int n = 0; n < 4; ++n)
                    acc[m][n] = fmaxf(acc[m][n], fmaf(x[m], f[n], w[n]));
        }
        __syncthreads();
    }

    // ---- epilogue: shuffle through LDS so atomics are lane-contiguous ----
#pragma unroll
    for (int m = 0; m < 4; ++m)
#pragma unroll
        for (int n = 0; n < 4; ++n)
            Os[4 * tx + m][4 * ty + n] = acc[m][n];
    __syncthreads();

#pragma unroll
    for (int c = 0; c < 16; ++c) {
        const int flat = c * 256 + tid;
        const int bl = flat >> 6;     // local b row
        const int ol = flat & 63;     // local o col — consecutive across lanes
        const unsigned key = enc_f32(Os[bl][ol]);
        atomicMax(&outk[(size_t)(bb + bl) * OUTDIM + ob + ol], key);
    }
}

__global__ __launch_bounds__(256)
void smp_decode_kernel(unsigned* __restrict__ data) {
    const int idx = blockIdx.x * 256 + threadIdx.x;
    uint4 v = reinterpret_cast<uint4*>(data)[idx];
    float4 o;
    o.x = dec_f32(v.x); o.y = dec_f32(v.y); o.z = dec_f32(v.z); o.w = dec_f32(v.w);
    reinterpret_cast<float4*>(data)[idx] = o;
}

extern "C" void kernel_launch(void* const* d_in, const int* in_sizes, int n_in,
                              void* d_out, int out_size, void* d_ws, size_t ws_size,
                              hipStream_t stream) {
    const float* X = (const float*)d_in[0];
    const float* W = (const float*)d_in[1];
    const float* F = (const float*)d_in[2];
    unsigned* outk = (unsigned*)d_out;

    // All valid keys are >= 0x00800000, so 0 is a safe "-inf" for atomicMax.
    hipMemsetAsync(d_out, 0, (size_t)out_size * sizeof(float), stream);

    dim3 grid(OUTDIM / BN, BDIM / BM, SPLITK);   // 16 x 8 x 4 = 512 blocks
    smp_main_kernel<<<grid, 256, 0, stream>>>(X, W, F, outk);

    const int nvec = out_size / 4;               // 131072 uint4s
    smp_decode_kernel<<<nvec / 256, 256, 0, stream>>>(outk);
}

// Round 2
// 92.033 us; speedup vs baseline: 1.0476x; 1.0476x over previous
//
#include <hip/hip_runtime.h>
#include <stdint.h>

// Tropical (max-plus) GEMM: out[b,o] = max_i ( W[o,i] + X[b,i] * factors[o] )
// B=512, OUT=1024, IN=1024, f32. VALU-bound (no max-MFMA exists).
// v2: 128x128 tile, 8x8 accs/thread (VALU:LDS = 2.7:1), row-major k-contiguous
// LDS with XOR chunk swizzle (no transpose staging, ~2-way read conflicts),
// splitK=16 -> 512 blocks (2/CU, 2 waves/SIMD), f32 partials in d_ws + combine.

#define BDIM 512
#define OUTDIM 1024
#define INDIM 1024
#define BM 128
#define BN 128
#define BK 64
#define SPLITK 16            // INDIM / BK
#define SLICE_F4 (BDIM * OUTDIM / 4)   // 131072 float4 per partial slice

__global__ __launch_bounds__(256, 2)
void smp_main_kernel(const float* __restrict__ X, const float* __restrict__ W,
                     const float* __restrict__ F, float* __restrict__ ws) {
    // Row-major, k-contiguous tiles; f4-chunk c of row r stored at c ^ ((r>>3)&7).
    // Read of rows 8*tx+m (fixed chunk) then spreads over 8 bank-groups: ~2-way.
    __shared__ float4 Xs[BM][BK / 4];   // 32 KB
    __shared__ float4 Ws[BN][BK / 4];   // 32 KB

    const int tid = threadIdx.x;
    const int tx = tid & 15;    // b-octet index (16 x 8 = 128 rows)
    const int ty = tid >> 4;    // o-octet index (16 x 8 = 128 cols)
    const int ob = blockIdx.x * BN;
    const int bb = blockIdx.y * BM;
    const int kb = blockIdx.z * BK;

    // ---- stage: both 128x64 tiles, coalesced f4 loads, b128 LDS writes ----
#pragma unroll
    for (int rr = 0; rr < 8; ++rr) {
        const int idx = tid + 256 * rr;      // 0..2047
        const int row = idx >> 4;            // 0..127
        const int c = idx & 15;              // f4 chunk along k
        const int cs = c ^ ((row >> 3) & 7); // XOR swizzle
        Xs[row][cs] = *reinterpret_cast<const float4*>(
            &X[(size_t)(bb + row) * INDIM + kb + 4 * c]);
        Ws[row][cs] = *reinterpret_cast<const float4*>(
            &W[(size_t)(ob + row) * INDIM + kb + 4 * c]);
    }

    float f[8];
#pragma unroll
    for (int n = 0; n < 8; ++n) f[n] = F[ob + 8 * ty + n];

    float acc[8][8];
#pragma unroll
    for (int m = 0; m < 8; ++m)
#pragma unroll
        for (int n = 0; n < 8; ++n) acc[m][n] = -INFINITY;

    __syncthreads();

    const int sx = tx & 7;
    const int sy = ty & 7;

    for (int i4 = 0; i4 < BK / 4; ++i4) {
        float xr[8][4], wr[8][4];
#pragma unroll
        for (int m = 0; m < 8; ++m) {
            const float4 v = Xs[8 * tx + m][i4 ^ sx];
            xr[m][0] = v.x; xr[m][1] = v.y; xr[m][2] = v.z; xr[m][3] = v.w;
        }
#pragma unroll
        for (int n = 0; n < 8; ++n) {
            const float4 v = Ws[8 * ty + n][i4 ^ sy];   // broadcast across tx
            wr[n][0] = v.x; wr[n][1] = v.y; wr[n][2] = v.z; wr[n][3] = v.w;
        }
#pragma unroll
        for (int j = 0; j < 4; ++j)
#pragma unroll
            for (int m = 0; m < 8; ++m)
#pragma unroll
                for (int n = 0; n < 8; ++n)
                    acc[m][n] = fmaxf(acc[m][n], fmaf(xr[m][j], f[n], wr[n][j]));
    }

    // ---- epilogue: f32 partials to ws[slice][b][o], f4 stores ----
    float* slice = ws + (size_t)blockIdx.z * BDIM * OUTDIM;
#pragma unroll
    for (int m = 0; m < 8; ++m) {
        float4 lo, hi;
        lo.x = acc[m][0]; lo.y = acc[m][1]; lo.z = acc[m][2]; lo.w = acc[m][3];
        hi.x = acc[m][4]; hi.y = acc[m][5]; hi.z = acc[m][6]; hi.w = acc[m][7];
        float* p = &slice[(size_t)(bb + 8 * tx + m) * OUTDIM + ob + 8 * ty];
        *reinterpret_cast<float4*>(p) = lo;
        *reinterpret_cast<float4*>(p + 4) = hi;
    }
}

__global__ __launch_bounds__(256)
void smp_combine_kernel(const float4* __restrict__ ws, float4* __restrict__ out) {
    const int idx = blockIdx.x * 256 + threadIdx.x;   // 0..SLICE_F4-1
    float4 m = ws[idx];
#pragma unroll
    for (int s = 1; s < SPLITK; ++s) {
        const float4 v = ws[idx + (size_t)s * SLICE_F4];
        m.x = fmaxf(m.x, v.x); m.y = fmaxf(m.y, v.y);
        m.z = fmaxf(m.z, v.z); m.w = fmaxf(m.w, v.w);
    }
    out[idx] = m;
}

extern "C" void kernel_launch(void* const* d_in, const int* in_sizes, int n_in,
                              void* d_out, int out_size, void* d_ws, size_t ws_size,
                              hipStream_t stream) {
    const float* X = (const float*)d_in[0];
    const float* W = (const float*)d_in[1];
    const float* F = (const float*)d_in[2];

    dim3 grid(OUTDIM / BN, BDIM / BM, SPLITK);   // 8 x 4 x 16 = 512 blocks
    smp_main_kernel<<<grid, 256, 0, stream>>>(X, W, F, (float*)d_ws);

    smp_combine_kernel<<<SLICE_F4 / 256, 256, 0, stream>>>(
        (const float4*)d_ws, (float4*)d_out);
}

// Round 3
// 90.844 us; speedup vs baseline: 1.0613x; 1.0131x over previous
//
#include <hip/hip_runtime.h>
#include <stdint.h>

// Tropical (max-plus) GEMM: out[b,o] = max_i ( W[o,i] + X[b,i] * factors[o] )
// B=512, OUT=1024, IN=1024, f32. VALU-bound (no max-MFMA exists).
// v3: global_load_lds staging (linear LDS dest + inverse-swizzled global src),
// 128x128 tile, 8x8 accs/thread, splitK=16 (512 blocks, 2/CU), bf16 partials
// in d_ws, bit-twiddle bf16 encode/decode, vectorized combine.

#define BDIM 512
#define OUTDIM 1024
#define INDIM 1024
#define BM 128
#define BN 128
#define BK 64
#define SPLITK 16
#define NCHUNK (BK / 4)                    // 16 f4-chunks per row
#define SLICE_U4 (BDIM * OUTDIM / 8)       // 65536 uint4 per bf16 partial slice

typedef uint32_t u32;
typedef unsigned short ushort_t;

__device__ __forceinline__ void gload_lds16(const float* g, void* l) {
    __builtin_amdgcn_global_load_lds(
        (const __attribute__((address_space(1))) u32*)g,
        (__attribute__((address_space(3))) u32*)l, 16, 0, 0);
}

// round-to-nearest-even f32 -> bf16 (finite inputs only)
__device__ __forceinline__ ushort_t f32_to_bf16(float x) {
    u32 u = __float_as_uint(x);
    u32 r = (u + 0x7FFFu + ((u >> 16) & 1u)) >> 16;
    return (ushort_t)r;
}

__global__ __launch_bounds__(256, 2)
void smp_main_kernel(const float* __restrict__ X, const float* __restrict__ W,
                     const float* __restrict__ F, ushort_t* __restrict__ ws) {
    // Linear [row][chunk] f4 tiles (32 KB each). LDS slot (row,c) holds
    // global chunk c ^ ((row>>3)&7)  => read of chunk i4 uses index i4 ^ swz.
    __shared__ float4 Xs[BM][NCHUNK];
    __shared__ float4 Ws[BN][NCHUNK];

    const int tid = threadIdx.x;
    const int tx = tid & 15;    // b-octet (16 x 8 = 128 rows)
    const int ty = tid >> 4;    // o-octet (16 x 8 = 128 cols)
    const int ob = blockIdx.x * BN;
    const int bb = blockIdx.y * BM;
    const int kb = blockIdx.z * BK;

    // ---- async stage: LDS dest is lane-linear, global src pre-swizzled ----
#pragma unroll
    for (int rr = 0; rr < 8; ++rr) {
        const int idx = rr * 256 + tid;        // 0..2047, linear in (wave,lane)
        const int row = idx >> 4;              // 0..127
        const int c = idx & 15;                // f4 chunk slot
        const int cg = c ^ ((row >> 3) & 7);   // which global chunk lands here
        gload_lds16(&X[(size_t)(bb + row) * INDIM + kb + 4 * cg], &Xs[row][c]);
        gload_lds16(&W[(size_t)(ob + row) * INDIM + kb + 4 * cg], &Ws[row][c]);
    }

    float f[8];
#pragma unroll
    for (int n = 0; n < 8; ++n) f[n] = F[ob + 8 * ty + n];

    float acc[8][8];
#pragma unroll
    for (int m = 0; m < 8; ++m)
#pragma unroll
        for (int n = 0; n < 8; ++n) acc[m][n] = -INFINITY;

    __syncthreads();   // drains vmcnt for the global_load_lds queue

    const int sx = tx & 7;      // swizzle of rows 8*tx..8*tx+7
    const int sy = ty & 7;

#pragma unroll
    for (int i4 = 0; i4 < NCHUNK; ++i4) {
        float xr[8][4], wr[8][4];
#pragma unroll
        for (int m = 0; m < 8; ++m) {
            const float4 v = Xs[8 * tx + m][i4 ^ sx];
            xr[m][0] = v.x; xr[m][1] = v.y; xr[m][2] = v.z; xr[m][3] = v.w;
        }
#pragma unroll
        for (int n = 0; n < 8; ++n) {
            const float4 v = Ws[8 * ty + n][i4 ^ sy];   // broadcast across tx
            wr[n][0] = v.x; wr[n][1] = v.y; wr[n][2] = v.z; wr[n][3] = v.w;
        }
#pragma unroll
        for (int j = 0; j < 4; ++j)
#pragma unroll
            for (int m = 0; m < 8; ++m)
#pragma unroll
                for (int n = 0; n < 8; ++n)
                    acc[m][n] = fmaxf(acc[m][n], fmaf(xr[m][j], f[n], wr[n][j]));
    }

    // ---- epilogue: bf16 partials, 16B stores ----
    ushort_t* slice = ws + (size_t)blockIdx.z * BDIM * OUTDIM;
#pragma unroll
    for (int m = 0; m < 8; ++m) {
        union { ushort_t u[8]; uint4 v; } pk;
#pragma unroll
        for (int n = 0; n < 8; ++n) pk.u[n] = f32_to_bf16(acc[m][n]);
        *reinterpret_cast<uint4*>(
            &slice[(size_t)(bb + 8 * tx + m) * OUTDIM + ob + 8 * ty]) = pk.v;
    }
}

__global__ __launch_bounds__(256)
void smp_combine_kernel(const uint4* __restrict__ ws, float4* __restrict__ out) {
    const int idx = blockIdx.x * 256 + threadIdx.x;   // 8 outputs per thread
    float m[8];
#pragma unroll
    for (int n = 0; n < 8; ++n) m[n] = -INFINITY;
#pragma unroll
    for (int s = 0; s < SPLITK; ++s) {
        const uint4 v = ws[(size_t)s * SLICE_U4 + idx];
        const u32 w[4] = {v.x, v.y, v.z, v.w};
#pragma unroll
        for (int p = 0; p < 4; ++p) {
            m[2 * p]     = fmaxf(m[2 * p],     __uint_as_float(w[p] << 16));
            m[2 * p + 1] = fmaxf(m[2 * p + 1], __uint_as_float(w[p] & 0xFFFF0000u));
        }
    }
    float4 o0, o1;
    o0.x = m[0]; o0.y = m[1]; o0.z = m[2]; o0.w = m[3];
    o1.x = m[4]; o1.y = m[5]; o1.z = m[6]; o1.w = m[7];
    out[2 * idx] = o0;
    out[2 * idx + 1] = o1;
}

extern "C" void kernel_launch(void* const* d_in, const int* in_sizes, int n_in,
                              void* d_out, int out_size, void* d_ws, size_t ws_size,
                              hipStream_t stream) {
    const float* X = (const float*)d_in[0];
    const float* W = (const float*)d_in[1];
    const float* F = (const float*)d_in[2];

    dim3 grid(OUTDIM / BN, BDIM / BM, SPLITK);   // 8 x 4 x 16 = 512 blocks
    smp_main_kernel<<<grid, 256, 0, stream>>>(X, W, F, (ushort_t*)d_ws);

    smp_combine_kernel<<<SLICE_U4 / 256, 256, 0, stream>>>(
        (const uint4*)d_ws, (float4*)d_out);
}

// Round 4
// 90.826 us; speedup vs baseline: 1.0615x; 1.0002x over previous
//
#include <hip/hip_runtime.h>
#include <stdint.h>

// Tropical (max-plus) GEMM: out[b,o] = max_i ( W[o,i] + X[b,i] * factors[o] )
// B=512, OUT=1024, IN=1024, f32. VALU-bound (no max-MFMA exists).
// v4: v_max3_f32 pairing (1.5 VALU/elem instead of 2), i4 unroll capped at 2
// (I-cache-resident body; v3's full unroll was ~64KB straight-line code).
// Same structure as v3: global_load_lds staging w/ inverse-swizzled source,
// 128x128 tile, 8x8 accs, splitK=16 (512 blocks, 2/CU), bf16 partials+combine.

#define BDIM 512
#define OUTDIM 1024
#define INDIM 1024
#define BM 128
#define BN 128
#define BK 64
#define SPLITK 16
#define NCHUNK (BK / 4)                    // 16 f4-chunks per row
#define SLICE_U4 (BDIM * OUTDIM / 8)       // 65536 uint4 per bf16 partial slice

typedef uint32_t u32;
typedef unsigned short ushort_t;

__device__ __forceinline__ void gload_lds16(const float* g, void* l) {
    __builtin_amdgcn_global_load_lds(
        (const __attribute__((address_space(1))) u32*)g,
        (__attribute__((address_space(3))) u32*)l, 16, 0, 0);
}

// round-to-nearest-even f32 -> bf16 (finite inputs only)
__device__ __forceinline__ ushort_t f32_to_bf16(float x) {
    u32 u = __float_as_uint(x);
    u32 r = (u + 0x7FFFu + ((u >> 16) & 1u)) >> 16;
    return (ushort_t)r;
}

__global__ __launch_bounds__(256, 2)
void smp_main_kernel(const float* __restrict__ X, const float* __restrict__ W,
                     const float* __restrict__ F, ushort_t* __restrict__ ws) {
    // Linear [row][chunk] f4 tiles (32 KB each). LDS slot (row,c) holds
    // global chunk c ^ ((row>>3)&7)  => read of chunk i4 uses index i4 ^ swz.
    __shared__ float4 Xs[BM][NCHUNK];
    __shared__ float4 Ws[BN][NCHUNK];

    const int tid = threadIdx.x;
    const int tx = tid & 15;    // b-octet (16 x 8 = 128 rows)
    const int ty = tid >> 4;    // o-octet (16 x 8 = 128 cols)
    const int ob = blockIdx.x * BN;
    const int bb = blockIdx.y * BM;
    const int kb = blockIdx.z * BK;

    // ---- async stage: LDS dest is lane-linear, global src pre-swizzled ----
#pragma unroll
    for (int rr = 0; rr < 8; ++rr) {
        const int idx = rr * 256 + tid;        // 0..2047, linear in (wave,lane)
        const int row = idx >> 4;              // 0..127
        const int c = idx & 15;                // f4 chunk slot
        const int cg = c ^ ((row >> 3) & 7);   // which global chunk lands here
        gload_lds16(&X[(size_t)(bb + row) * INDIM + kb + 4 * cg], &Xs[row][c]);
        gload_lds16(&W[(size_t)(ob + row) * INDIM + kb + 4 * cg], &Ws[row][c]);
    }

    float f[8];
#pragma unroll
    for (int n = 0; n < 8; ++n) f[n] = F[ob + 8 * ty + n];

    float acc[8][8];
#pragma unroll
    for (int m = 0; m < 8; ++m)
#pragma unroll
        for (int n = 0; n < 8; ++n) acc[m][n] = -INFINITY;

    __syncthreads();   // drains vmcnt for the global_load_lds queue

    const int sx = tx & 7;      // swizzle of rows 8*tx..8*tx+7
    const int sy = ty & 7;

#pragma unroll 2
    for (int i4 = 0; i4 < NCHUNK; ++i4) {
        float xr[8][4], wr[8][4];
#pragma unroll
        for (int m = 0; m < 8; ++m) {
            const float4 v = Xs[8 * tx + m][i4 ^ sx];
            xr[m][0] = v.x; xr[m][1] = v.y; xr[m][2] = v.z; xr[m][3] = v.w;
        }
#pragma unroll
        for (int n = 0; n < 8; ++n) {
            const float4 v = Ws[8 * ty + n][i4 ^ sy];   // broadcast across tx
            wr[n][0] = v.x; wr[n][1] = v.y; wr[n][2] = v.z; wr[n][3] = v.w;
        }
        // 2 fma + 1 max3 per 2 k-steps: 1.5 VALU/element (max is associative).
#pragma unroll
        for (int jp = 0; jp < 2; ++jp)
#pragma unroll
            for (int m = 0; m < 8; ++m)
#pragma unroll
                for (int n = 0; n < 8; ++n) {
                    const float t0 = fmaf(xr[m][2 * jp],     f[n], wr[n][2 * jp]);
                    const float t1 = fmaf(xr[m][2 * jp + 1], f[n], wr[n][2 * jp + 1]);
                    acc[m][n] = fmaxf(acc[m][n], fmaxf(t0, t1));
                }
    }

    // ---- epilogue: bf16 partials, 16B stores ----
    ushort_t* slice = ws + (size_t)blockIdx.z * BDIM * OUTDIM;
#pragma unroll
    for (int m = 0; m < 8; ++m) {
        union { ushort_t u[8]; uint4 v; } pk;
#pragma unroll
        for (int n = 0; n < 8; ++n) pk.u[n] = f32_to_bf16(acc[m][n]);
        *reinterpret_cast<uint4*>(
            &slice[(size_t)(bb + 8 * tx + m) * OUTDIM + ob + 8 * ty]) = pk.v;
    }
}

__global__ __launch_bounds__(256)
void smp_combine_kernel(const uint4* __restrict__ ws, float4* __restrict__ out) {
    const int idx = blockIdx.x * 256 + threadIdx.x;   // 8 outputs per thread
    float m[8];
#pragma unroll
    for (int n = 0; n < 8; ++n) m[n] = -INFINITY;
#pragma unroll
    for (int s = 0; s < SPLITK; ++s) {
        const uint4 v = ws[(size_t)s * SLICE_U4 + idx];
        const u32 w[4] = {v.x, v.y, v.z, v.w};
#pragma unroll
        for (int p = 0; p < 4; ++p) {
            m[2 * p]     = fmaxf(m[2 * p],     __uint_as_float(w[p] << 16));
            m[2 * p + 1] = fmaxf(m[2 * p + 1], __uint_as_float(w[p] & 0xFFFF0000u));
        }
    }
    float4 o0, o1;
    o0.x = m[0]; o0.y = m[1]; o0.z = m[2]; o0.w = m[3];
    o1.x = m[4]; o1.y = m[5]; o1.z = m[6]; o1.w = m[7];
    out[2 * idx] = o0;
    out[2 * idx + 1] = o1;
}

extern "C" void kernel_launch(void* const* d_in, const int* in_sizes, int n_in,
                              void* d_out, int out_size, void* d_ws, size_t ws_size,
                              hipStream_t stream) {
    const float* X = (const float*)d_in[0];
    const float* W = (const float*)d_in[1];
    const float* F = (const float*)d_in[2];

    dim3 grid(OUTDIM / BN, BDIM / BM, SPLITK);   // 8 x 4 x 16 = 512 blocks
    smp_main_kernel<<<grid, 256, 0, stream>>>(X, W, F, (ushort_t*)d_ws);

    smp_combine_kernel<<<SLICE_U4 / 256, 256, 0, stream>>>(
        (const uint4*)d_ws, (float4*)d_out);
}